// Round 3
// baseline (95.822 us; speedup 1.0000x reference)
//
#include <hip/hip_runtime.h>

// Chamfer loss: x,y (16, 4096, 3) fp32 -> scalar.
//
// d(x,y) = ||x||^2 + (||y||^2 - 2 x.y); min over y only needs
//   t = fma(-x0,2y0, fma(-x1,2y1, fma(-x2,2y2, ||y||^2)))
// with (2y0,2y1,2y2,||y||^2) precomputed per y-point at LDS-staging time.
//
// Round-3 changes (from rocprof):
//  - The 256 MiB harness workspace poison (fillBufferAligned, ~43 us) is a
//    fixed in-stream cost; remaining lever is pass-1 time (~35 us observed).
//  - Pass 1 was LDS-throughput/latency-limited: 1 ds_read_b128 per y served
//    only 8 x-points (LDS demand ~86% of VALU demand; round-1 VALUBusy 55%).
//    Now XPT=16: each broadcast y-read feeds 16 x-points -> LDS ~43% of VALU.
//  - ||x||^2 recomputed in the epilogue instead of held live (-16 VGPR) to
//    stay under the 128-VGPR cap of __launch_bounds__(256, 4).
//  - Grid 16 batches x 64 y-chunks = 1024 blocks = 4 blocks/CU = 4 waves/SIMD.
//  - ws = 16*64*4096 floats (16.8 MB); round-2 NYC=16 store path and the
//    atomic path kept as ws_size fallbacks.

constexpr int NPTS   = 4096;
constexpr int NBATCH = 16;
constexpr int BLOCK  = 256;

// ---------------- main path: XPT=16, NYC=64 --------------------------------

constexpr int XPT16 = 16;                    // x-points per thread (covers 4096)
constexpr int NYC64 = 64;                    // y-chunks
constexpr int YT64  = NPTS / NYC64;          // 64 y-points per block (1 KB LDS)

__global__ __launch_bounds__(BLOCK, 4) void chamfer_part16_kernel(
    const float* __restrict__ x, const float* __restrict__ y,
    float* __restrict__ ws)
{
    __shared__ float4 sy[YT64];              // (2y0, 2y1, 2y2, ||y||^2)

    const int b      = blockIdx.x / NYC64;
    const int ychunk = blockIdx.x % NYC64;

    if (threadIdx.x < YT64) {
        const float* yp = y + ((size_t)b * NPTS + ychunk * YT64 + threadIdx.x) * 3;
        const float y0 = yp[0], y1 = yp[1], y2 = yp[2];
        sy[threadIdx.x] = make_float4(2.0f * y0, 2.0f * y1, 2.0f * y2,
                                      fmaf(y2, y2, fmaf(y1, y1, y0 * y0)));
    }

    // This thread's 16 consecutive x-points (48 floats = 12 float4).
    const int xbase = threadIdx.x * XPT16;
    const float4* xp4 = (const float4*)(x + ((size_t)b * NPTS + xbase) * 3);
    float xf[48];                            // xf[3*i+c] = coord c of x-point i
    #pragma unroll
    for (int q = 0; q < 12; ++q) {
        const float4 a = xp4[q];
        xf[4 * q + 0] = a.x; xf[4 * q + 1] = a.y;
        xf[4 * q + 2] = a.z; xf[4 * q + 3] = a.w;
    }

    __syncthreads();

    float m[XPT16];
    #pragma unroll
    for (int i = 0; i < XPT16; ++i) m[i] = 3.4e38f;

    #pragma unroll 2
    for (int j = 0; j < YT64; j += 2) {
        const float4 Y0 = sy[j];
        const float4 Y1 = sy[j + 1];
        #pragma unroll
        for (int i = 0; i < XPT16; ++i) {
            const float t0 = fmaf(-xf[3 * i + 0], Y0.x,
                             fmaf(-xf[3 * i + 1], Y0.y,
                             fmaf(-xf[3 * i + 2], Y0.z, Y0.w)));
            const float t1 = fmaf(-xf[3 * i + 0], Y1.x,
                             fmaf(-xf[3 * i + 1], Y1.y,
                             fmaf(-xf[3 * i + 2], Y1.z, Y1.w)));
            m[i] = fminf(fminf(t0, t1), m[i]);   // -> v_min3_f32
        }
    }

    // Epilogue: d = max(||x||^2 + min_t, 0), ||x||^2 recomputed here.
    float* wp = ws + ((size_t)b * NYC64 + ychunk) * NPTS + xbase;
    #pragma unroll
    for (int i = 0; i < XPT16; i += 4) {
        float4 o;
        float* oc = (float*)&o;
        #pragma unroll
        for (int k = 0; k < 4; ++k) {
            const int p = i + k;
            const float x2 = fmaf(xf[3 * p + 2], xf[3 * p + 2],
                             fmaf(xf[3 * p + 1], xf[3 * p + 1],
                                  xf[3 * p + 0] * xf[3 * p + 0]));
            oc[k] = fmaxf(x2 + m[p], 0.0f);
        }
        ((float4*)wp)[i / 4] = o;
    }
}

__global__ __launch_bounds__(BLOCK) void chamfer_reduce64_kernel(
    const float* __restrict__ ws, float* __restrict__ out)
{
    __shared__ float swsum[BLOCK / 64];
    const int idx = blockIdx.x * BLOCK + threadIdx.x;   // one x-point each
    const int b   = idx / NPTS;
    const int xp  = idx % NPTS;

    const float* p = ws + (size_t)b * NYC64 * NPTS + xp;
    float mn = 3.4e38f;
    #pragma unroll 8
    for (int yc = 0; yc < NYC64; ++yc)
        mn = fminf(mn, p[(size_t)yc * NPTS]);

    float s = mn;
    for (int off = 32; off > 0; off >>= 1)
        s += __shfl_down(s, off, 64);
    const int wave = threadIdx.x >> 6;
    if ((threadIdx.x & 63) == 0) swsum[wave] = s;
    __syncthreads();
    if (threadIdx.x == 0) {
        float t = 0.f;
        #pragma unroll
        for (int w = 0; w < BLOCK / 64; ++w) t += swsum[w];
        atomicAdd(out, t * (1.0f / NPTS));
    }
}

// ---------------- fallback A: round-2 store path (NYC=16) ------------------

constexpr int XPT    = 8;
constexpr int XCHUNK = BLOCK * XPT;          // 2048
constexpr int NXC    = NPTS / XCHUNK;        // 2

template <int NYC>
__global__ __launch_bounds__(BLOCK, 4) void chamfer_part_kernel(
    const float* __restrict__ x, const float* __restrict__ y,
    float* __restrict__ ws)
{
    constexpr int YTILE = NPTS / NYC;
    __shared__ float4 sy[YTILE];

    const int b      = blockIdx.x / (NXC * NYC);
    const int xchunk = (blockIdx.x / NYC) % NXC;
    const int ychunk = blockIdx.x % NYC;

    for (int i = threadIdx.x; i < YTILE; i += BLOCK) {
        const float* yp = y + ((size_t)b * NPTS + ychunk * YTILE + i) * 3;
        const float y0 = yp[0], y1 = yp[1], y2 = yp[2];
        sy[i] = make_float4(2.0f * y0, 2.0f * y1, 2.0f * y2,
                            fmaf(y2, y2, fmaf(y1, y1, y0 * y0)));
    }

    const int xbase = xchunk * XCHUNK + threadIdx.x * XPT;
    const float4* xp4 = (const float4*)(x + ((size_t)b * NPTS + xbase) * 3);
    const float4 a0 = xp4[0], a1 = xp4[1], a2 = xp4[2];
    const float4 a3 = xp4[3], a4 = xp4[4], a5 = xp4[5];
    const float xa[XPT][3] = {
        {a0.x, a0.y, a0.z}, {a0.w, a1.x, a1.y},
        {a1.z, a1.w, a2.x}, {a2.y, a2.z, a2.w},
        {a3.x, a3.y, a3.z}, {a3.w, a4.x, a4.y},
        {a4.z, a4.w, a5.x}, {a5.y, a5.z, a5.w}};

    float x2s[XPT];
    #pragma unroll
    for (int i = 0; i < XPT; ++i)
        x2s[i] = fmaf(xa[i][2], xa[i][2],
                 fmaf(xa[i][1], xa[i][1], xa[i][0] * xa[i][0]));

    __syncthreads();

    float m[XPT];
    #pragma unroll
    for (int i = 0; i < XPT; ++i) m[i] = 3.4e38f;

    #pragma unroll 2
    for (int j = 0; j < YTILE; j += 2) {
        const float4 Y0 = sy[j];
        const float4 Y1 = sy[j + 1];
        #pragma unroll
        for (int i = 0; i < XPT; ++i) {
            const float t0 = fmaf(-xa[i][0], Y0.x,
                             fmaf(-xa[i][1], Y0.y,
                             fmaf(-xa[i][2], Y0.z, Y0.w)));
            const float t1 = fmaf(-xa[i][0], Y1.x,
                             fmaf(-xa[i][1], Y1.y,
                             fmaf(-xa[i][2], Y1.z, Y1.w)));
            m[i] = fminf(fminf(t0, t1), m[i]);
        }
    }

    float* wp = ws + ((size_t)b * NYC + ychunk) * NPTS + xbase;
    #pragma unroll
    for (int i = 0; i < XPT; i += 4) {
        float4 o;
        float* oc = (float*)&o;
        #pragma unroll
        for (int k = 0; k < 4; ++k)
            oc[k] = fmaxf(x2s[i + k] + m[i + k], 0.0f);
        ((float4*)wp)[i / 4] = o;
    }
}

template <int NYC>
__global__ __launch_bounds__(BLOCK) void chamfer_reduce_kernel(
    const float* __restrict__ ws, float* __restrict__ out)
{
    __shared__ float swsum[BLOCK / 64];
    const int idx = blockIdx.x * BLOCK + threadIdx.x;
    const int b   = idx / NPTS;
    const int xp  = idx % NPTS;

    float mn = 3.4e38f;
    #pragma unroll
    for (int yc = 0; yc < NYC; ++yc)
        mn = fminf(mn, ws[((size_t)b * NYC + yc) * NPTS + xp]);

    float s = mn;
    for (int off = 32; off > 0; off >>= 1)
        s += __shfl_down(s, off, 64);
    const int wave = threadIdx.x >> 6;
    if ((threadIdx.x & 63) == 0) swsum[wave] = s;
    __syncthreads();
    if (threadIdx.x == 0) {
        float t = 0.f;
        #pragma unroll
        for (int w = 0; w < BLOCK / 64; ++w) t += swsum[w];
        atomicAdd(out, t * (1.0f / NPTS));
    }
}

// ---------------- fallback B: atomic path (tiny ws) ------------------------

__global__ __launch_bounds__(BLOCK) void chamfer_min_atomic_kernel(
    const float* __restrict__ x, const float* __restrict__ y,
    unsigned int* __restrict__ ws_min)
{
    constexpr int YTILE = 256;
    constexpr int NYC   = NPTS / YTILE;
    __shared__ float4 sy[YTILE];

    const int b      = blockIdx.x / (NXC * NYC);
    const int xchunk = (blockIdx.x / NYC) % NXC;
    const int ychunk = blockIdx.x % NYC;

    {
        const float* yp = y + ((size_t)b * NPTS + ychunk * YTILE + threadIdx.x) * 3;
        const float y0 = yp[0], y1 = yp[1], y2 = yp[2];
        sy[threadIdx.x] = make_float4(2.0f * y0, 2.0f * y1, 2.0f * y2,
                                      fmaf(y2, y2, fmaf(y1, y1, y0 * y0)));
    }

    const int xbase = xchunk * XCHUNK + threadIdx.x * XPT;
    const float4* xp4 = (const float4*)(x + ((size_t)b * NPTS + xbase) * 3);
    const float4 a0 = xp4[0], a1 = xp4[1], a2 = xp4[2];
    const float4 a3 = xp4[3], a4 = xp4[4], a5 = xp4[5];
    const float xa[XPT][3] = {
        {a0.x, a0.y, a0.z}, {a0.w, a1.x, a1.y},
        {a1.z, a1.w, a2.x}, {a2.y, a2.z, a2.w},
        {a3.x, a3.y, a3.z}, {a3.w, a4.x, a4.y},
        {a4.z, a4.w, a5.x}, {a5.y, a5.z, a5.w}};

    float x2s[XPT];
    #pragma unroll
    for (int i = 0; i < XPT; ++i)
        x2s[i] = fmaf(xa[i][2], xa[i][2],
                 fmaf(xa[i][1], xa[i][1], xa[i][0] * xa[i][0]));

    __syncthreads();

    float m[XPT];
    #pragma unroll
    for (int i = 0; i < XPT; ++i) m[i] = 3.4e38f;

    #pragma unroll 2
    for (int j = 0; j < YTILE; j += 2) {
        const float4 Y0 = sy[j];
        const float4 Y1 = sy[j + 1];
        #pragma unroll
        for (int i = 0; i < XPT; ++i) {
            const float t0 = fmaf(-xa[i][0], Y0.x,
                             fmaf(-xa[i][1], Y0.y,
                             fmaf(-xa[i][2], Y0.z, Y0.w)));
            const float t1 = fmaf(-xa[i][0], Y1.x,
                             fmaf(-xa[i][1], Y1.y,
                             fmaf(-xa[i][2], Y1.z, Y1.w)));
            m[i] = fminf(m[i], fminf(t0, t1));
        }
    }

    unsigned int* wm = ws_min + (size_t)b * NPTS + xbase;
    #pragma unroll
    for (int i = 0; i < XPT; ++i) {
        const float d = fmaxf(x2s[i] + m[i], 0.0f);
        atomicMin(&wm[i], __float_as_uint(d));
    }
}

__global__ __launch_bounds__(BLOCK) void chamfer_sum_kernel(
    const unsigned int* __restrict__ ws_min, float* __restrict__ out)
{
    __shared__ float swsum[BLOCK / 64];
    const int total = NBATCH * NPTS;
    float s = 0.f;
    for (int i = blockIdx.x * BLOCK + threadIdx.x; i < total;
         i += gridDim.x * BLOCK)
        s += __uint_as_float(ws_min[i]);

    for (int off = 32; off > 0; off >>= 1)
        s += __shfl_down(s, off, 64);
    const int wave = threadIdx.x >> 6;
    if ((threadIdx.x & 63) == 0) swsum[wave] = s;
    __syncthreads();
    if (threadIdx.x == 0) {
        float t = 0.f;
        #pragma unroll
        for (int w = 0; w < BLOCK / 64; ++w) t += swsum[w];
        atomicAdd(out, t * (1.0f / NPTS));
    }
}

// ---------------- host ------------------------------------------------------

extern "C" void kernel_launch(void* const* d_in, const int* in_sizes, int n_in,
                              void* d_out, int out_size, void* d_ws, size_t ws_size,
                              hipStream_t stream) {
    const float* x = (const float*)d_in[0];
    const float* y = (const float*)d_in[1];
    float* out = (float*)d_out;

    hipMemsetAsync(out, 0, sizeof(float), stream);

    const size_t need64 = (size_t)NBATCH * NYC64 * NPTS * sizeof(float); // 16.8 MB
    const size_t need16 = (size_t)NBATCH * 16 * NPTS * sizeof(float);    //  4.2 MB

    if (ws_size >= need64) {
        float* ws = (float*)d_ws;
        chamfer_part16_kernel<<<NBATCH * NYC64, BLOCK, 0, stream>>>(x, y, ws);
        chamfer_reduce64_kernel<<<NBATCH * NPTS / BLOCK, BLOCK, 0, stream>>>(ws, out);
    } else if (ws_size >= need16) {
        float* ws = (float*)d_ws;
        chamfer_part_kernel<16><<<NBATCH * NXC * 16, BLOCK, 0, stream>>>(x, y, ws);
        chamfer_reduce_kernel<16><<<NBATCH * NPTS / BLOCK, BLOCK, 0, stream>>>(ws, out);
    } else {
        unsigned int* ws_min = (unsigned int*)d_ws;
        hipMemsetAsync(ws_min, 0xFF, (size_t)NBATCH * NPTS * sizeof(unsigned int),
                       stream);
        chamfer_min_atomic_kernel<<<NBATCH * NXC * 16, BLOCK, 0, stream>>>(
            x, y, ws_min);
        chamfer_sum_kernel<<<64, BLOCK, 0, stream>>>(ws_min, out);
    }
}